// Round 1
// baseline (45.163 us; speedup 1.0000x reference)
//
#include <hip/hip_runtime.h>
#include <math.h>

// Problem constants (fixed by setup_inputs)
#define BATCH 4
#define NPTS  2048
#define CHAN  32
#define CONVF 332.07156

// Main-kernel geometry
#define MAIN_BLOCKS 2048
#define MAIN_THREADS 256

// --- Kernel A: per-point embedding dot products ---------------------------
// aj[bn] = dot(embs[bn], w[0:C])   (the "j" term)
// ai[bn] = dot(embs[bn], w[C:2C])  (the "i" term)
__global__ void precompute_embdots(const float* __restrict__ embs,
                                   const float* __restrict__ sfw,
                                   float* __restrict__ aj,
                                   float* __restrict__ ai) {
    int idx = blockIdx.x * blockDim.x + threadIdx.x;
    if (idx >= BATCH * NPTS) return;
    const float* e = embs + (size_t)idx * CHAN;
    float sj = 0.f, si = 0.f;
#pragma unroll
    for (int k = 0; k < CHAN; ++k) {
        float ev = e[k];
        sj = fmaf(ev, sfw[k], sj);
        si = fmaf(ev, sfw[CHAN + k], si);
    }
    aj[idx] = sj;
    ai[idx] = si;
}

// --- Kernel B: pair energies, block-partial reduction ---------------------
__global__ __launch_bounds__(MAIN_THREADS) void pair_energy(
    const float* __restrict__ X,    // (B,N,3)
    const float* __restrict__ qs,   // (N,)
    const float* __restrict__ Ps,   // (N,3)
    const float* __restrict__ mask, // (B,N,N)
    const float* __restrict__ aj,   // (B,N)
    const float* __restrict__ ai,   // (B,N)
    const float* __restrict__ sfw,  // (2C+1,)
    double* __restrict__ partials)  // (gridDim.x,)
{
    const float wd = sfw[2 * CHAN];          // scalar, cached
    const int GROUPS = BATCH * NPTS * (NPTS / 4); // 4,194,304
    int gstart = blockIdx.x * blockDim.x + threadIdx.x;
    int gstride = gridDim.x * blockDim.x;

    double acc = 0.0;
    for (int g = gstart; g < GROUPS; g += gstride) {
        int row = g >> 9;           // b*N + i   (N/4 = 512 groups per row)
        int j0  = (g & 511) << 2;   // first j of this group of 4
        int b   = row >> 11;
        int i   = row & (NPTS - 1);

        // i-side (wave-uniform within a row)
        float xi = X[row * 3 + 0];
        float yi = X[row * 3 + 1];
        float zi = X[row * 3 + 2];
        float qi = qs[i];
        float Pix = Ps[i * 3 + 0];
        float Piy = Ps[i * 3 + 1];
        float Piz = Ps[i * 3 + 2];
        float aii = ai[row];

        float4 m4 = *reinterpret_cast<const float4*>(mask + (size_t)row * NPTS + j0);
        float mv[4] = {m4.x, m4.y, m4.z, m4.w};

        float esum = 0.f;
#pragma unroll
        for (int t = 0; t < 4; ++t) {
            int j  = j0 + t;
            int cj = b * NPTS + j;

            // V = X[j] - X[i]
            float dx = X[cj * 3 + 0] - xi;
            float dy = X[cj * 3 + 1] - yi;
            float dz = X[cj * 3 + 2] - zi;

            // D = sqrt(sum(V*V + 1e-6)) = sqrt(|V|^2 + 3e-6)
            float d2 = fmaf(dx, dx, fmaf(dy, dy, fmaf(dz, dz, 3e-6f)));
            float D  = sqrtf(d2);
            float invD = __builtin_amdgcn_rcpf(D + 1e-6f);

            // Vn = (V + 1e-6) / ||V + 1e-6||   (norm >= ~1.7e-6 > 1e-12 clamp)
            float vpx = dx + 1e-6f, vpy = dy + 1e-6f, vpz = dz + 1e-6f;
            float np2 = fmaf(vpx, vpx, fmaf(vpy, vpy, vpz * vpz));
            float rn  = __builtin_amdgcn_rsqf(np2);

            float OqP = fmaf(vpx, Pix, fmaf(vpy, Piy, vpz * Piz)) * rn;
            float Pjx = Ps[j * 3 + 0];
            float Pjy = Ps[j * 3 + 1];
            float Pjz = Ps[j * 3 + 2];
            float OPP = fmaf(Pix, Pjx, fmaf(Piy, Pjy, Piz * Pjz));
            float Q12 = qi * qs[j];

            float sf = aj[cj] + aii + invD * wd;

            float invD2 = invD * invD;
            float invD3 = invD2 * invD;
            float invD4 = invD2 * invD2;
            float invD6 = invD3 * invD3;

            float E = Q12 * invD * sf + OqP * invD4 + OPP * invD6;
            esum = fmaf(mv[t], E, esum);
        }
        acc += (double)esum;
    }

    // block reduction in LDS (doubles)
    __shared__ double sdata[MAIN_THREADS];
    sdata[threadIdx.x] = acc;
    __syncthreads();
#pragma unroll
    for (int s = MAIN_THREADS / 2; s > 0; s >>= 1) {
        if (threadIdx.x < s) sdata[threadIdx.x] += sdata[threadIdx.x + s];
        __syncthreads();
    }
    if (threadIdx.x == 0) partials[blockIdx.x] = sdata[0];
}

// --- Kernel C: final reduction + scale + NaN guard ------------------------
__global__ void finalize(const double* __restrict__ partials, int n,
                         float* __restrict__ out) {
    __shared__ double sdata[256];
    double a = 0.0;
    for (int i = threadIdx.x; i < n; i += 256) a += partials[i];
    sdata[threadIdx.x] = a;
    __syncthreads();
#pragma unroll
    for (int s = 128; s > 0; s >>= 1) {
        if (threadIdx.x < s) sdata[threadIdx.x] += sdata[threadIdx.x + s];
        __syncthreads();
    }
    if (threadIdx.x == 0) {
        double tot = sdata[0] * (double)CONVF * 0.5;
        float f = (float)tot;
        out[0] = isnan(f) ? 1e-6f : f;
    }
}

extern "C" void kernel_launch(void* const* d_in, const int* in_sizes, int n_in,
                              void* d_out, int out_size, void* d_ws, size_t ws_size,
                              hipStream_t stream) {
    const float* X    = (const float*)d_in[0];
    const float* embs = (const float*)d_in[1];
    const float* qs   = (const float*)d_in[2];
    const float* Ps   = (const float*)d_in[3];
    const float* mask = (const float*)d_in[4];
    const float* sfw  = (const float*)d_in[5];
    float* out = (float*)d_out;

    // workspace layout: [ partials: double[MAIN_BLOCKS] | aj: float[B*N] | ai: float[B*N] ]
    double* partials = (double*)d_ws;
    float* aj = (float*)(partials + MAIN_BLOCKS);
    float* ai = aj + BATCH * NPTS;

    precompute_embdots<<<(BATCH * NPTS + 255) / 256, 256, 0, stream>>>(embs, sfw, aj, ai);
    pair_energy<<<MAIN_BLOCKS, MAIN_THREADS, 0, stream>>>(X, qs, Ps, mask, aj, ai, sfw, partials);
    finalize<<<1, 256, 0, stream>>>(partials, MAIN_BLOCKS, out);
}

// Round 2
// 36.871 us; speedup vs baseline: 1.2249x; 1.2249x over previous
//
#include <hip/hip_runtime.h>
#include <math.h>

// Problem constants (fixed by setup_inputs)
#define BATCH 4
#define NPTS  2048
#define CHAN  32
#define CONVF 332.07156

#define MAIN_THREADS 256
#define ROWS_PER_BLOCK 4
#define MAIN_BLOCKS ((BATCH * NPTS) / ROWS_PER_BLOCK)   // 2048

// --- Kernel A: pack per-(b,n) j-side data + i-side embedding dot ----------
// pk[bn] = {x, y, z, q, Px, Py, Pz, aj}   (two float4s)
// ai[bn] = dot(embs[bn], w[C:2C])
__global__ void pack_points(const float* __restrict__ X,
                            const float* __restrict__ embs,
                            const float* __restrict__ qs,
                            const float* __restrict__ Ps,
                            const float* __restrict__ sfw,
                            float4* __restrict__ pk,   // (B*N*2)
                            float* __restrict__ ai) {
    int idx = blockIdx.x * blockDim.x + threadIdx.x;
    if (idx >= BATCH * NPTS) return;
    int n = idx & (NPTS - 1);
    const float* e = embs + (size_t)idx * CHAN;
    float sj = 0.f, si = 0.f;
#pragma unroll
    for (int k = 0; k < CHAN; ++k) {
        float ev = e[k];
        sj = fmaf(ev, sfw[k], sj);
        si = fmaf(ev, sfw[CHAN + k], si);
    }
    float4 a, b;
    a.x = X[idx * 3 + 0];
    a.y = X[idx * 3 + 1];
    a.z = X[idx * 3 + 2];
    a.w = qs[n];
    b.x = Ps[n * 3 + 0];
    b.y = Ps[n * 3 + 1];
    b.z = Ps[n * 3 + 2];
    b.w = sj;                      // aj
    pk[idx * 2 + 0] = a;
    pk[idx * 2 + 1] = b;
    ai[idx] = si;
}

// --- Kernel B: 4-row x 4-j tiles, block-partial reduction -----------------
__global__ __launch_bounds__(MAIN_THREADS) void pair_energy(
    const float4* __restrict__ pk,   // (B*N*2)
    const float* __restrict__ ai,    // (B*N)
    const float4* __restrict__ mask4,// (B*N*N/4)
    const float* __restrict__ sfw,   // (2C+1,)
    double* __restrict__ partials)   // (MAIN_BLOCKS,)
{
    const float wd = sfw[2 * CHAN];
    const int r0 = blockIdx.x * ROWS_PER_BLOCK;   // global row = b*N + i
    const int b  = r0 >> 11;                      // batch (rows same batch)
    const int jbase = b * NPTS;

    // i-side for 4 rows (wave-uniform, registers)
    float xi[ROWS_PER_BLOCK], yi[ROWS_PER_BLOCK], zi[ROWS_PER_BLOCK], qi[ROWS_PER_BLOCK];
    float Pix[ROWS_PER_BLOCK], Piy[ROWS_PER_BLOCK], Piz[ROWS_PER_BLOCK], aii[ROWS_PER_BLOCK];
#pragma unroll
    for (int r = 0; r < ROWS_PER_BLOCK; ++r) {
        float4 a = pk[(r0 + r) * 2 + 0];
        float4 p = pk[(r0 + r) * 2 + 1];
        xi[r] = a.x; yi[r] = a.y; zi[r] = a.z; qi[r] = a.w;
        Pix[r] = p.x; Piy[r] = p.y; Piz[r] = p.z;
        aii[r] = ai[r0 + r];
    }

    double acc[ROWS_PER_BLOCK];
#pragma unroll
    for (int r = 0; r < ROWS_PER_BLOCK; ++r) acc[r] = 0.0;

    // threads cover 512 j-quads in NPTS/4/MAIN_THREADS = 2 iterations
#pragma unroll
    for (int iter = 0; iter < NPTS / 4 / MAIN_THREADS; ++iter) {
        int jq = iter * MAIN_THREADS + threadIdx.x;   // j-quad index
        int j0 = jq * 4;

        // j-side packed loads (4 j, 2 float4 each)
        float4 ja[4], jb[4];
#pragma unroll
        for (int t = 0; t < 4; ++t) {
            ja[t] = pk[(jbase + j0 + t) * 2 + 0];
            jb[t] = pk[(jbase + j0 + t) * 2 + 1];
        }
        // mask rows (coalesced float4 per row)
        float4 m[ROWS_PER_BLOCK];
#pragma unroll
        for (int r = 0; r < ROWS_PER_BLOCK; ++r)
            m[r] = mask4[((size_t)(r0 + r) * NPTS >> 2) + jq];

#pragma unroll
        for (int r = 0; r < ROWS_PER_BLOCK; ++r) {
            float mv[4] = {m[r].x, m[r].y, m[r].z, m[r].w};
            float es = 0.f;
#pragma unroll
            for (int t = 0; t < 4; ++t) {
                float dx = ja[t].x - xi[r];
                float dy = ja[t].y - yi[r];
                float dz = ja[t].z - zi[r];
                // D^2 = |V|^2 + 3e-6 ; invD ~= 1/sqrt(D^2)
                float d2 = fmaf(dx, dx, fmaf(dy, dy, fmaf(dz, dz, 3e-6f)));
                float invD = __builtin_amdgcn_rsqf(d2);
                // Vn direction from V + 1e-6
                float vpx = dx + 1e-6f, vpy = dy + 1e-6f, vpz = dz + 1e-6f;
                float np2 = fmaf(vpx, vpx, fmaf(vpy, vpy, vpz * vpz));
                float rn  = __builtin_amdgcn_rsqf(np2);
                float OqP = fmaf(vpx, Pix[r], fmaf(vpy, Piy[r], vpz * Piz[r]));
                float OPP = fmaf(Pix[r], jb[t].x, fmaf(Piy[r], jb[t].y, Piz[r] * jb[t].z));
                float Q12 = qi[r] * ja[t].w;
                float sf  = fmaf(invD, wd, aii[r] + jb[t].w);
                float invD2 = invD * invD;
                float invD4 = invD2 * invD2;
                float invD6 = invD4 * invD2;
                float E = fmaf(Q12 * invD, sf,
                          fmaf(OqP * rn, invD4, OPP * invD6));
                es = fmaf(mv[t], E, es);
            }
            acc[r] += (double)es;
        }
    }

    double tacc = 0.0;
#pragma unroll
    for (int r = 0; r < ROWS_PER_BLOCK; ++r) tacc += acc[r];

    __shared__ double sdata[MAIN_THREADS];
    sdata[threadIdx.x] = tacc;
    __syncthreads();
#pragma unroll
    for (int s = MAIN_THREADS / 2; s > 0; s >>= 1) {
        if (threadIdx.x < s) sdata[threadIdx.x] += sdata[threadIdx.x + s];
        __syncthreads();
    }
    if (threadIdx.x == 0) partials[blockIdx.x] = sdata[0];
}

// --- Kernel C: final reduction + scale + NaN guard ------------------------
__global__ void finalize(const double* __restrict__ partials, int n,
                         float* __restrict__ out) {
    __shared__ double sdata[256];
    double a = 0.0;
    for (int i = threadIdx.x; i < n; i += 256) a += partials[i];
    sdata[threadIdx.x] = a;
    __syncthreads();
#pragma unroll
    for (int s = 128; s > 0; s >>= 1) {
        if (threadIdx.x < s) sdata[threadIdx.x] += sdata[threadIdx.x + s];
        __syncthreads();
    }
    if (threadIdx.x == 0) {
        double tot = sdata[0] * (double)CONVF * 0.5;
        float f = (float)tot;
        out[0] = isnan(f) ? 1e-6f : f;
    }
}

extern "C" void kernel_launch(void* const* d_in, const int* in_sizes, int n_in,
                              void* d_out, int out_size, void* d_ws, size_t ws_size,
                              hipStream_t stream) {
    const float* X    = (const float*)d_in[0];
    const float* embs = (const float*)d_in[1];
    const float* qs   = (const float*)d_in[2];
    const float* Ps   = (const float*)d_in[3];
    const float* mask = (const float*)d_in[4];
    const float* sfw  = (const float*)d_in[5];
    float* out = (float*)d_out;

    // workspace: [ partials double[2048] | pk float4[B*N*2] | ai float[B*N] ]
    double* partials = (double*)d_ws;
    float4* pk = (float4*)(partials + MAIN_BLOCKS);
    float*  ai = (float*)(pk + BATCH * NPTS * 2);

    pack_points<<<(BATCH * NPTS + 255) / 256, 256, 0, stream>>>(X, embs, qs, Ps, sfw, pk, ai);
    pair_energy<<<MAIN_BLOCKS, MAIN_THREADS, 0, stream>>>(pk, ai, (const float4*)mask, sfw, partials);
    finalize<<<1, 256, 0, stream>>>(partials, MAIN_BLOCKS, out);
}

// Round 3
// 29.526 us; speedup vs baseline: 1.5296x; 1.2488x over previous
//
#include <hip/hip_runtime.h>
#include <math.h>

// Problem constants (fixed by setup_inputs)
#define BATCH 4
#define NPTS  2048
#define CHAN  32
#define CONVF 332.07156

#define ROWS 8
#define THREADS 256
#define NBLOCKS ((BATCH * NPTS / ROWS) * 2)   // 2048: (rowblk, jhalf)

// --- Kernel A: pack per-(b,n) j-side data + i-side embedding dot ----------
// pk[bn] = {x, y, z, q} , {Px, Py, Pz, aj}
// ai[bn] = dot(embs[bn], w[C:2C])
__global__ void pack_points(const float* __restrict__ X,
                            const float* __restrict__ embs,
                            const float* __restrict__ qs,
                            const float* __restrict__ Ps,
                            const float* __restrict__ sfw,
                            float4* __restrict__ pk,   // (B*N*2)
                            float* __restrict__ ai) {
    int idx = blockIdx.x * blockDim.x + threadIdx.x;
    if (idx >= BATCH * NPTS) return;
    int n = idx & (NPTS - 1);
    const float* e = embs + (size_t)idx * CHAN;
    float sj = 0.f, si = 0.f;
#pragma unroll
    for (int k = 0; k < CHAN; ++k) {
        float ev = e[k];
        sj = fmaf(ev, sfw[k], sj);
        si = fmaf(ev, sfw[CHAN + k], si);
    }
    float4 a, b;
    a.x = X[idx * 3 + 0];
    a.y = X[idx * 3 + 1];
    a.z = X[idx * 3 + 2];
    a.w = qs[n];
    b.x = Ps[n * 3 + 0];
    b.y = Ps[n * 3 + 1];
    b.z = Ps[n * 3 + 2];
    b.w = sj;                      // aj
    pk[idx * 2 + 0] = a;
    pk[idx * 2 + 1] = b;
    ai[idx] = si;
}

// --- Kernel B: 8-row x 4-j per thread, single load burst ------------------
__global__ __launch_bounds__(THREADS, 2) void pair_energy(
    const float4* __restrict__ pk,   // (B*N*2)
    const float* __restrict__ ai,    // (B*N)
    const float4* __restrict__ mask4,// (B*N*N/4)
    const float* __restrict__ sfw,   // (2C+1,)
    double* __restrict__ partials)   // (NBLOCKS,)
{
    const float wd = sfw[2 * CHAN];
    const int rowblk = blockIdx.x >> 1;
    const int jhalf  = blockIdx.x & 1;
    const int r0 = rowblk * ROWS;          // global row = b*N + i
    const int b  = r0 >> 11;
    const int jbase = b * NPTS;
    const int jq = jhalf * THREADS + threadIdx.x;   // j-quad index 0..511
    const int j0 = jq << 2;

    // ---- one burst of 16 independent float4 loads ----
    // mask: 8 rows, coalesced 1KB/row per wave (HBM-streaming)
    float4 m[ROWS];
#pragma unroll
    for (int r = 0; r < ROWS; ++r)
        m[r] = mask4[(size_t)(r0 + r) * (NPTS / 4) + jq];
    // j-side packed point data (L1/L2-resident)
    float4 ja[4], jb[4];
#pragma unroll
    for (int t = 0; t < 4; ++t) {
        ja[t] = pk[(jbase + j0 + t) * 2 + 0];
        jb[t] = pk[(jbase + j0 + t) * 2 + 1];
    }

    // ---- compute: 8 rows x 4 pairs ----
    double acc = 0.0;
#pragma unroll
    for (int r = 0; r < ROWS; ++r) {
        // i-side: block-uniform -> scalar loads / SGPRs
        float4 a = pk[(r0 + r) * 2 + 0];
        float4 p = pk[(r0 + r) * 2 + 1];
        float aw = ai[r0 + r];
        float cP = 1e-6f * (p.x + p.y + p.z);   // eps-dot, row-constant
        float mv[4] = {m[r].x, m[r].y, m[r].z, m[r].w};
        float es = 0.f;
#pragma unroll
        for (int t = 0; t < 4; ++t) {
            float dx = ja[t].x - a.x;
            float dy = ja[t].y - a.y;
            float dz = ja[t].z - a.z;
            float d2 = fmaf(dx, dx, fmaf(dy, dy, fmaf(dz, dz, 3e-6f)));
            float invD = __builtin_amdgcn_rsqf(d2);   // ~ 1/(D+1e-6), also ~ 1/|V+eps|
            float OqP = fmaf(dx, p.x, fmaf(dy, p.y, fmaf(dz, p.z, cP)));
            float OPP = fmaf(p.x, jb[t].x, fmaf(p.y, jb[t].y, p.z * jb[t].z));
            float Q12 = a.w * ja[t].w;
            float sf  = fmaf(invD, wd, aw + jb[t].w);
            float invD2 = invD * invD;
            float invD4 = invD2 * invD2;
            float invD5 = invD4 * invD;
            float invD6 = invD4 * invD2;
            float E = fmaf(Q12 * invD, sf,
                      fmaf(OqP, invD5, OPP * invD6));
            es = fmaf(mv[t], E, es);
        }
        acc += (double)es;
    }

    // ---- block reduction ----
    __shared__ double sdata[THREADS];
    sdata[threadIdx.x] = acc;
    __syncthreads();
#pragma unroll
    for (int s = THREADS / 2; s > 0; s >>= 1) {
        if (threadIdx.x < s) sdata[threadIdx.x] += sdata[threadIdx.x + s];
        __syncthreads();
    }
    if (threadIdx.x == 0) partials[blockIdx.x] = sdata[0];
}

// --- Kernel C: final reduction + scale + NaN guard ------------------------
__global__ void finalize(const double* __restrict__ partials, int n,
                         float* __restrict__ out) {
    __shared__ double sdata[256];
    double a = 0.0;
    for (int i = threadIdx.x; i < n; i += 256) a += partials[i];
    sdata[threadIdx.x] = a;
    __syncthreads();
#pragma unroll
    for (int s = 128; s > 0; s >>= 1) {
        if (threadIdx.x < s) sdata[threadIdx.x] += sdata[threadIdx.x + s];
        __syncthreads();
    }
    if (threadIdx.x == 0) {
        double tot = sdata[0] * (double)CONVF * 0.5;
        float f = (float)tot;
        out[0] = isnan(f) ? 1e-6f : f;
    }
}

extern "C" void kernel_launch(void* const* d_in, const int* in_sizes, int n_in,
                              void* d_out, int out_size, void* d_ws, size_t ws_size,
                              hipStream_t stream) {
    const float* X    = (const float*)d_in[0];
    const float* embs = (const float*)d_in[1];
    const float* qs   = (const float*)d_in[2];
    const float* Ps   = (const float*)d_in[3];
    const float* mask = (const float*)d_in[4];
    const float* sfw  = (const float*)d_in[5];
    float* out = (float*)d_out;

    // workspace: [ partials double[NBLOCKS] | pk float4[B*N*2] | ai float[B*N] ]
    double* partials = (double*)d_ws;
    float4* pk = (float4*)(partials + NBLOCKS);
    float*  ai = (float*)(pk + BATCH * NPTS * 2);

    pack_points<<<(BATCH * NPTS + 255) / 256, 256, 0, stream>>>(X, embs, qs, Ps, sfw, pk, ai);
    pair_energy<<<NBLOCKS, THREADS, 0, stream>>>(pk, ai, (const float4*)mask, sfw, partials);
    finalize<<<1, 256, 0, stream>>>(partials, NBLOCKS, out);
}